// Round 10
// baseline (222.410 us; speedup 1.0000x reference)
//
#include <hip/hip_runtime.h>

// CustomPuzzleLoss: loss1 = mean|p - t|, loss2 = 0.1 * dup_count/B over 5x5
// grids (rows+cols, exact float equality, "seen earlier" semantics),
// +1000 if any p outside [0.5, 5.5]. Output: single float scalar.
//
// R10 (single-variable): R8 changed two things at once (launch_bounds(256,1)
// VGPR budget + nontemporal loads) and won 18 us. nt loads may be forcing
// ALL traffic to HBM (no L3 service; R1-R6 showed L3 serving half) and get
// deprioritized. This round: identical to R9 but with PLAIN loads.
// Keeps LB(256,1) + 2-stage prefetch pipeline + barrier-free structure.

#define BLOCK 256
#define WPB 4                     // waves per block
#define TILE 1600                 // floats per wave-tile = 64 grids * 25
#define NBLOCKS 1536              // 6 blocks/CU by LDS

typedef float v4f __attribute__((ext_vector_type(4)));
typedef int   v4i __attribute__((ext_vector_type(4)));

struct TileRegs {
    v4f p[6];
    v4i t[6];
    float ptl;
    int   ttl;
};

__device__ __forceinline__ void load_tile(const float* __restrict__ preds,
                                          const int* __restrict__ tgts,
                                          long long t, int lane, TileRegs& r) {
    const v4f* __restrict__ p4 = (const v4f*)(preds + t * TILE);
    const v4i* __restrict__ t4 = (const v4i*)(tgts  + t * TILE);
    #pragma unroll
    for (int k = 0; k < 6; ++k) r.p[k] = p4[lane + 64 * k];
    #pragma unroll
    for (int k = 0; k < 6; ++k) r.t[k] = t4[lane + 64 * k];
    r.ptl = preds[t * TILE + 1536 + lane];
    r.ttl = tgts [t * TILE + 1536 + lane];
}

// dup count for one 5x5 grid (pointer into LDS; compiler folds the loads)
__device__ __forceinline__ int grid_dups(const float* __restrict__ p) {
    int ldup = 0;
    #pragma unroll
    for (int r = 0; r < 5; ++r) {           // rows
        const float a = p[r*5+0], b = p[r*5+1], c = p[r*5+2],
                    d = p[r*5+3], e = p[r*5+4];
        ldup += (int)(b == a);
        ldup += (int)((c == a) | (c == b));
        ldup += (int)((d == a) | (d == b) | (d == c));
        ldup += (int)((e == a) | (e == b) | (e == c) | (e == d));
    }
    #pragma unroll
    for (int q = 0; q < 5; ++q) {           // cols
        const float a = p[q+0], b = p[q+5], c = p[q+10],
                    d = p[q+15], e = p[q+20];
        ldup += (int)(b == a);
        ldup += (int)((c == a) | (c == b));
        ldup += (int)((d == a) | (d == b) | (d == c));
        ldup += (int)((e == a) | (e == b) | (e == c) | (e == d));
    }
    return ldup;
}

__device__ __forceinline__ void compute_tile(const TileRegs& r,
                                             float* __restrict__ wp,
                                             v4f* __restrict__ wp4,
                                             int lane, float& lsum, int& ldup,
                                             float& mn, float& mx) {
    #pragma unroll
    for (int k = 0; k < 6; ++k) {
        wp4[lane + 64 * k] = r.p[k];
        lsum += fabsf(r.p[k].x - (float)r.t[k].x);
        lsum += fabsf(r.p[k].y - (float)r.t[k].y);
        lsum += fabsf(r.p[k].z - (float)r.t[k].z);
        lsum += fabsf(r.p[k].w - (float)r.t[k].w);
        mn = fminf(mn, fminf(fminf(r.p[k].x, r.p[k].y), fminf(r.p[k].z, r.p[k].w)));
        mx = fmaxf(mx, fmaxf(fmaxf(r.p[k].x, r.p[k].y), fmaxf(r.p[k].z, r.p[k].w)));
    }
    wp[1536 + lane] = r.ptl;
    lsum += fabsf(r.ptl - (float)r.ttl);
    mn = fminf(mn, r.ptl);
    mx = fmaxf(mx, r.ptl);

    // dup pass: lane owns grid `lane` = 25 consecutive floats in the wave's
    // own LDS slice (stride 25 = 2-way bank aliasing, free). Wave reads only
    // its own writes -> compiler-managed lgkmcnt ordering, no barrier.
    ldup += grid_dups(wp + lane * 25);
}

__global__ __launch_bounds__(BLOCK, 1) void puzzle_main(
    const float* __restrict__ preds, const int* __restrict__ tgts,
    long long n_total,
    float* __restrict__ blk_sum, int* __restrict__ blk_dup,
    int* __restrict__ blk_oob)
{
    __shared__ float lds_p[WPB * TILE];     // 25600 B: one 6.4KB slice/wave
    __shared__ float s_sum[WPB];
    __shared__ int   s_dup[WPB];
    __shared__ int   s_oob[WPB];

    const int tid  = threadIdx.x;
    const int lane = tid & 63;
    const int wv   = tid >> 6;

    const long long total_tiles = n_total / TILE;
    const int total_waves = gridDim.x * WPB;
    const int gwave = blockIdx.x * WPB + wv;

    float* __restrict__ wp = &lds_p[wv * TILE];
    v4f* __restrict__ wp4 = reinterpret_cast<v4f*>(wp);

    float lsum = 0.0f;
    int   ldup = 0;
    float mn =  1e30f;
    float mx = -1e30f;

    // --- 2-stage software pipeline over this wave's tiles ---
    long long t0 = gwave;
    if (t0 < total_tiles) {
        TileRegs cur, nxt;
        load_tile(preds, tgts, t0, lane, cur);
        __builtin_amdgcn_sched_barrier(0);
        for (long long tn = t0 + total_waves; tn < total_tiles; tn += total_waves) {
            load_tile(preds, tgts, tn, lane, nxt);       // prefetch t+1
            __builtin_amdgcn_sched_barrier(0);           // pin: loads stay above
            compute_tile(cur, wp, wp4, lane, lsum, ldup, mn, mx);
            cur = nxt;                                   // register copy
        }
        compute_tile(cur, wp, wp4, lane, lsum, ldup, mn, mx);
    }

    // ragged tail (n % TILE != 0; n always a multiple of 25): direct global.
    const long long rem = n_total - total_tiles * TILE;
    if (rem > 0 && gwave == total_waves - 1) {
        const int ngrids = (int)(rem / 25);
        if (lane < ngrids) {
            const float* sp = preds + total_tiles * TILE + (long long)lane * 25;
            const int*   st = tgts  + total_tiles * TILE + (long long)lane * 25;
            float q[25];
            #pragma unroll
            for (int j = 0; j < 25; ++j) q[j] = sp[j];
            #pragma unroll
            for (int j = 0; j < 25; ++j) {
                lsum += fabsf(q[j] - (float)st[j]);
                mn = fminf(mn, q[j]);
                mx = fmaxf(mx, q[j]);
            }
            ldup += grid_dups(q);
        }
    }

    // wave reduction
    #pragma unroll
    for (int off = 32; off > 0; off >>= 1) {
        lsum += __shfl_down(lsum, off, 64);
        ldup += __shfl_down(ldup, off, 64);
        mn = fminf(mn, __shfl_down(mn, off, 64));
        mx = fmaxf(mx, __shfl_down(mx, off, 64));
    }
    if (lane == 0) {
        s_sum[wv] = lsum;
        s_dup[wv] = ldup;
        s_oob[wv] = (int)((mn < 0.5f) | (mx > 5.5f));
    }
    __syncthreads();
    if (tid == 0) {
        float bs = 0.0f; int bd = 0, bo = 0;
        #pragma unroll
        for (int w = 0; w < WPB; ++w) { bs += s_sum[w]; bd += s_dup[w]; bo |= s_oob[w]; }
        blk_sum[blockIdx.x] = bs;
        blk_dup[blockIdx.x] = bd;
        blk_oob[blockIdx.x] = bo;
    }
}

#define FBLOCK 256
#define FNWAVES (FBLOCK / 64)

__global__ __launch_bounds__(FBLOCK) void puzzle_final(
    const float* __restrict__ blk_sum, const int* __restrict__ blk_dup,
    const int* __restrict__ blk_oob, int nblocks,
    long long n_total, long long batch, float* __restrict__ out)
{
    __shared__ double s_sum[FNWAVES];
    __shared__ int    s_dup[FNWAVES];
    __shared__ int    s_oob[FNWAVES];

    double lsum = 0.0;
    int ldup = 0, loob = 0;
    for (int i = threadIdx.x; i < nblocks; i += FBLOCK) {
        lsum += (double)blk_sum[i];
        ldup += blk_dup[i];
        loob |= blk_oob[i];
    }
    #pragma unroll
    for (int off = 32; off > 0; off >>= 1) {
        lsum += __shfl_down(lsum, off, 64);
        ldup += __shfl_down(ldup, off, 64);
        loob |= __shfl_down(loob, off, 64);
    }
    const int wave = threadIdx.x >> 6;
    if ((threadIdx.x & 63) == 0) { s_sum[wave] = lsum; s_dup[wave] = ldup; s_oob[wave] = loob; }
    __syncthreads();
    if (threadIdx.x == 0) {
        double bs = 0.0; int bd = 0, bo = 0;
        #pragma unroll
        for (int w = 0; w < FNWAVES; ++w) { bs += s_sum[w]; bd += s_dup[w]; bo |= s_oob[w]; }
        const float loss1 = (float)(bs / (double)n_total);
        const float loss2 = (float)((double)bd * 0.1 / (double)batch);
        out[0] = loss1 + loss2 + (bo ? 1000.0f : 0.0f);
    }
}

extern "C" void kernel_launch(void* const* d_in, const int* in_sizes, int n_in,
                              void* d_out, int out_size, void* d_ws, size_t ws_size,
                              hipStream_t stream) {
    const float* preds = (const float*)d_in[0];
    const int*   tgts  = (const int*)d_in[1];
    float* out = (float*)d_out;

    const long long n = (long long)in_sizes[0];
    const long long batch = n / 25;

    // workspace layout: [float sums | int dups | int oobs], each NBLOCKS long
    float* blk_sum = (float*)d_ws;
    int*   blk_dup = (int*)(blk_sum + NBLOCKS);
    int*   blk_oob = (int*)(blk_dup + NBLOCKS);

    puzzle_main<<<NBLOCKS, BLOCK, 0, stream>>>(preds, tgts, n,
                                               blk_sum, blk_dup, blk_oob);
    puzzle_final<<<1, FBLOCK, 0, stream>>>(blk_sum, blk_dup, blk_oob,
                                           NBLOCKS, n, batch, out);
}

// Round 11
// 215.398 us; speedup vs baseline: 1.0326x; 1.0326x over previous
//
#include <hip/hip_runtime.h>

// CustomPuzzleLoss: loss1 = mean|p - t|, loss2 = 0.1 * dup_count/B over 5x5
// grids (rows+cols, exact float equality, "seen earlier" semantics),
// +1000 if any p outside [0.5, 5.5]. Output: single float scalar.
//
// R11 (hybrid): R10 proved the entire R8 win was __builtin_nontemporal_load
// (plain loads -> 80 us / 1.3 TB/s regardless of structure; nt -> ~60 us).
// With plain loads L3 serves ~half the input (FETCH 102 of 210 MB, thanks to
// the harness's input restore). This round splits the streams: preds = nt
// (HBM-streamed, no-allocate), targets = plain (L3-served) — aiming for
// parallel L3 + HBM service. Everything else identical to R9 (best config).

#define BLOCK 256
#define WPB 4                     // waves per block
#define TILE 1600                 // floats per wave-tile = 64 grids * 25
#define NBLOCKS 1536              // 6 blocks/CU by LDS

typedef float v4f __attribute__((ext_vector_type(4)));
typedef int   v4i __attribute__((ext_vector_type(4)));

struct TileRegs {
    v4f p[6];
    v4i t[6];
    float ptl;
    int   ttl;
};

__device__ __forceinline__ void load_tile(const float* __restrict__ preds,
                                          const int* __restrict__ tgts,
                                          long long t, int lane, TileRegs& r) {
    const v4f* __restrict__ p4 = (const v4f*)(preds + t * TILE);
    const v4i* __restrict__ t4 = (const v4i*)(tgts  + t * TILE);
    #pragma unroll
    for (int k = 0; k < 6; ++k) r.p[k] = __builtin_nontemporal_load(&p4[lane + 64 * k]);
    #pragma unroll
    for (int k = 0; k < 6; ++k) r.t[k] = t4[lane + 64 * k];      // plain: L3-served
    r.ptl = __builtin_nontemporal_load(&preds[t * TILE + 1536 + lane]);
    r.ttl = tgts [t * TILE + 1536 + lane];
}

// dup count for one 5x5 grid (pointer into LDS; compiler folds the loads)
__device__ __forceinline__ int grid_dups(const float* __restrict__ p) {
    int ldup = 0;
    #pragma unroll
    for (int r = 0; r < 5; ++r) {           // rows
        const float a = p[r*5+0], b = p[r*5+1], c = p[r*5+2],
                    d = p[r*5+3], e = p[r*5+4];
        ldup += (int)(b == a);
        ldup += (int)((c == a) | (c == b));
        ldup += (int)((d == a) | (d == b) | (d == c));
        ldup += (int)((e == a) | (e == b) | (e == c) | (e == d));
    }
    #pragma unroll
    for (int q = 0; q < 5; ++q) {           // cols
        const float a = p[q+0], b = p[q+5], c = p[q+10],
                    d = p[q+15], e = p[q+20];
        ldup += (int)(b == a);
        ldup += (int)((c == a) | (c == b));
        ldup += (int)((d == a) | (d == b) | (d == c));
        ldup += (int)((e == a) | (e == b) | (e == c) | (e == d));
    }
    return ldup;
}

__device__ __forceinline__ void compute_tile(const TileRegs& r,
                                             float* __restrict__ wp,
                                             v4f* __restrict__ wp4,
                                             int lane, float& lsum, int& ldup,
                                             float& mn, float& mx) {
    #pragma unroll
    for (int k = 0; k < 6; ++k) {
        wp4[lane + 64 * k] = r.p[k];
        lsum += fabsf(r.p[k].x - (float)r.t[k].x);
        lsum += fabsf(r.p[k].y - (float)r.t[k].y);
        lsum += fabsf(r.p[k].z - (float)r.t[k].z);
        lsum += fabsf(r.p[k].w - (float)r.t[k].w);
        mn = fminf(mn, fminf(fminf(r.p[k].x, r.p[k].y), fminf(r.p[k].z, r.p[k].w)));
        mx = fmaxf(mx, fmaxf(fmaxf(r.p[k].x, r.p[k].y), fmaxf(r.p[k].z, r.p[k].w)));
    }
    wp[1536 + lane] = r.ptl;
    lsum += fabsf(r.ptl - (float)r.ttl);
    mn = fminf(mn, r.ptl);
    mx = fmaxf(mx, r.ptl);

    // dup pass: lane owns grid `lane` = 25 consecutive floats in the wave's
    // own LDS slice (stride 25 = 2-way bank aliasing, free). Wave reads only
    // its own writes -> compiler-managed lgkmcnt ordering, no barrier.
    ldup += grid_dups(wp + lane * 25);
}

__global__ __launch_bounds__(BLOCK, 1) void puzzle_main(
    const float* __restrict__ preds, const int* __restrict__ tgts,
    long long n_total,
    float* __restrict__ blk_sum, int* __restrict__ blk_dup,
    int* __restrict__ blk_oob)
{
    __shared__ float lds_p[WPB * TILE];     // 25600 B: one 6.4KB slice/wave
    __shared__ float s_sum[WPB];
    __shared__ int   s_dup[WPB];
    __shared__ int   s_oob[WPB];

    const int tid  = threadIdx.x;
    const int lane = tid & 63;
    const int wv   = tid >> 6;

    const long long total_tiles = n_total / TILE;
    const int total_waves = gridDim.x * WPB;
    const int gwave = blockIdx.x * WPB + wv;

    float* __restrict__ wp = &lds_p[wv * TILE];
    v4f* __restrict__ wp4 = reinterpret_cast<v4f*>(wp);

    float lsum = 0.0f;
    int   ldup = 0;
    float mn =  1e30f;
    float mx = -1e30f;

    // --- 2-stage software pipeline over this wave's tiles ---
    long long t0 = gwave;
    if (t0 < total_tiles) {
        TileRegs cur, nxt;
        load_tile(preds, tgts, t0, lane, cur);
        __builtin_amdgcn_sched_barrier(0);
        for (long long tn = t0 + total_waves; tn < total_tiles; tn += total_waves) {
            load_tile(preds, tgts, tn, lane, nxt);       // prefetch t+1
            __builtin_amdgcn_sched_barrier(0);           // pin: loads stay above
            compute_tile(cur, wp, wp4, lane, lsum, ldup, mn, mx);
            cur = nxt;                                   // register copy
        }
        compute_tile(cur, wp, wp4, lane, lsum, ldup, mn, mx);
    }

    // ragged tail (n % TILE != 0; n always a multiple of 25): direct global.
    const long long rem = n_total - total_tiles * TILE;
    if (rem > 0 && gwave == total_waves - 1) {
        const int ngrids = (int)(rem / 25);
        if (lane < ngrids) {
            const float* sp = preds + total_tiles * TILE + (long long)lane * 25;
            const int*   st = tgts  + total_tiles * TILE + (long long)lane * 25;
            float q[25];
            #pragma unroll
            for (int j = 0; j < 25; ++j) q[j] = sp[j];
            #pragma unroll
            for (int j = 0; j < 25; ++j) {
                lsum += fabsf(q[j] - (float)st[j]);
                mn = fminf(mn, q[j]);
                mx = fmaxf(mx, q[j]);
            }
            ldup += grid_dups(q);
        }
    }

    // wave reduction
    #pragma unroll
    for (int off = 32; off > 0; off >>= 1) {
        lsum += __shfl_down(lsum, off, 64);
        ldup += __shfl_down(ldup, off, 64);
        mn = fminf(mn, __shfl_down(mn, off, 64));
        mx = fmaxf(mx, __shfl_down(mx, off, 64));
    }
    if (lane == 0) {
        s_sum[wv] = lsum;
        s_dup[wv] = ldup;
        s_oob[wv] = (int)((mn < 0.5f) | (mx > 5.5f));
    }
    __syncthreads();
    if (tid == 0) {
        float bs = 0.0f; int bd = 0, bo = 0;
        #pragma unroll
        for (int w = 0; w < WPB; ++w) { bs += s_sum[w]; bd += s_dup[w]; bo |= s_oob[w]; }
        blk_sum[blockIdx.x] = bs;
        blk_dup[blockIdx.x] = bd;
        blk_oob[blockIdx.x] = bo;
    }
}

#define FBLOCK 256
#define FNWAVES (FBLOCK / 64)

__global__ __launch_bounds__(FBLOCK) void puzzle_final(
    const float* __restrict__ blk_sum, const int* __restrict__ blk_dup,
    const int* __restrict__ blk_oob, int nblocks,
    long long n_total, long long batch, float* __restrict__ out)
{
    __shared__ double s_sum[FNWAVES];
    __shared__ int    s_dup[FNWAVES];
    __shared__ int    s_oob[FNWAVES];

    double lsum = 0.0;
    int ldup = 0, loob = 0;
    for (int i = threadIdx.x; i < nblocks; i += FBLOCK) {
        lsum += (double)blk_sum[i];
        ldup += blk_dup[i];
        loob |= blk_oob[i];
    }
    #pragma unroll
    for (int off = 32; off > 0; off >>= 1) {
        lsum += __shfl_down(lsum, off, 64);
        ldup += __shfl_down(ldup, off, 64);
        loob |= __shfl_down(loob, off, 64);
    }
    const int wave = threadIdx.x >> 6;
    if ((threadIdx.x & 63) == 0) { s_sum[wave] = lsum; s_dup[wave] = ldup; s_oob[wave] = loob; }
    __syncthreads();
    if (threadIdx.x == 0) {
        double bs = 0.0; int bd = 0, bo = 0;
        #pragma unroll
        for (int w = 0; w < FNWAVES; ++w) { bs += s_sum[w]; bd += s_dup[w]; bo |= s_oob[w]; }
        const float loss1 = (float)(bs / (double)n_total);
        const float loss2 = (float)((double)bd * 0.1 / (double)batch);
        out[0] = loss1 + loss2 + (bo ? 1000.0f : 0.0f);
    }
}

extern "C" void kernel_launch(void* const* d_in, const int* in_sizes, int n_in,
                              void* d_out, int out_size, void* d_ws, size_t ws_size,
                              hipStream_t stream) {
    const float* preds = (const float*)d_in[0];
    const int*   tgts  = (const int*)d_in[1];
    float* out = (float*)d_out;

    const long long n = (long long)in_sizes[0];
    const long long batch = n / 25;

    // workspace layout: [float sums | int dups | int oobs], each NBLOCKS long
    float* blk_sum = (float*)d_ws;
    int*   blk_dup = (int*)(blk_sum + NBLOCKS);
    int*   blk_oob = (int*)(blk_dup + NBLOCKS);

    puzzle_main<<<NBLOCKS, BLOCK, 0, stream>>>(preds, tgts, n,
                                               blk_sum, blk_dup, blk_oob);
    puzzle_final<<<1, FBLOCK, 0, stream>>>(blk_sum, blk_dup, blk_oob,
                                           NBLOCKS, n, batch, out);
}

// Round 12
// 201.283 us; speedup vs baseline: 1.1050x; 1.0701x over previous
//
#include <hip/hip_runtime.h>

// CustomPuzzleLoss: loss1 = mean|p - t|, loss2 = 0.1 * dup_count/B over 5x5
// grids (rows+cols, exact float equality, "seen earlier" semantics),
// +1000 if any p outside [0.5, 5.5]. Output: single float scalar.
//
// R12: R11 showed (a) all-nt beats any plain-load mix (plain pollutes L3 and
// slows the harness phases; L3 service buys nothing because the allocate
// path is the throttle), (b) main ~61 us = 3.4 TB/s vs ~6.3 achievable.
// Gap theory: 2.67 tiles/wave means 1/3 of tiles pay full unhidden latency.
// Fix: NBLOCKS=768 (3 blocks/CU, 12 waves/CU), 5.33 tiles/wave -> 81% of
// tile boundaries covered by the 2-stage prefetch pipeline. All-nt loads.

#define BLOCK 256
#define WPB 4                     // waves per block
#define TILE 1600                 // floats per wave-tile = 64 grids * 25
#define NBLOCKS 768               // 3 blocks/CU; 12 waves/CU; 5.33 tiles/wave

typedef float v4f __attribute__((ext_vector_type(4)));
typedef int   v4i __attribute__((ext_vector_type(4)));

struct TileRegs {
    v4f p[6];
    v4i t[6];
    float ptl;
    int   ttl;
};

__device__ __forceinline__ void load_tile(const float* __restrict__ preds,
                                          const int* __restrict__ tgts,
                                          long long t, int lane, TileRegs& r) {
    const v4f* __restrict__ p4 = (const v4f*)(preds + t * TILE);
    const v4i* __restrict__ t4 = (const v4i*)(tgts  + t * TILE);
    #pragma unroll
    for (int k = 0; k < 6; ++k) r.p[k] = __builtin_nontemporal_load(&p4[lane + 64 * k]);
    #pragma unroll
    for (int k = 0; k < 6; ++k) r.t[k] = __builtin_nontemporal_load(&t4[lane + 64 * k]);
    r.ptl = __builtin_nontemporal_load(&preds[t * TILE + 1536 + lane]);
    r.ttl = __builtin_nontemporal_load(&tgts [t * TILE + 1536 + lane]);
}

// dup count for one 5x5 grid (pointer into LDS; compiler folds the loads)
__device__ __forceinline__ int grid_dups(const float* __restrict__ p) {
    int ldup = 0;
    #pragma unroll
    for (int r = 0; r < 5; ++r) {           // rows
        const float a = p[r*5+0], b = p[r*5+1], c = p[r*5+2],
                    d = p[r*5+3], e = p[r*5+4];
        ldup += (int)(b == a);
        ldup += (int)((c == a) | (c == b));
        ldup += (int)((d == a) | (d == b) | (d == c));
        ldup += (int)((e == a) | (e == b) | (e == c) | (e == d));
    }
    #pragma unroll
    for (int q = 0; q < 5; ++q) {           // cols
        const float a = p[q+0], b = p[q+5], c = p[q+10],
                    d = p[q+15], e = p[q+20];
        ldup += (int)(b == a);
        ldup += (int)((c == a) | (c == b));
        ldup += (int)((d == a) | (d == b) | (d == c));
        ldup += (int)((e == a) | (e == b) | (e == c) | (e == d));
    }
    return ldup;
}

__device__ __forceinline__ void compute_tile(const TileRegs& r,
                                             float* __restrict__ wp,
                                             v4f* __restrict__ wp4,
                                             int lane, float& lsum, int& ldup,
                                             float& mn, float& mx) {
    #pragma unroll
    for (int k = 0; k < 6; ++k) {
        wp4[lane + 64 * k] = r.p[k];
        lsum += fabsf(r.p[k].x - (float)r.t[k].x);
        lsum += fabsf(r.p[k].y - (float)r.t[k].y);
        lsum += fabsf(r.p[k].z - (float)r.t[k].z);
        lsum += fabsf(r.p[k].w - (float)r.t[k].w);
        mn = fminf(mn, fminf(fminf(r.p[k].x, r.p[k].y), fminf(r.p[k].z, r.p[k].w)));
        mx = fmaxf(mx, fmaxf(fmaxf(r.p[k].x, r.p[k].y), fmaxf(r.p[k].z, r.p[k].w)));
    }
    wp[1536 + lane] = r.ptl;
    lsum += fabsf(r.ptl - (float)r.ttl);
    mn = fminf(mn, r.ptl);
    mx = fmaxf(mx, r.ptl);

    // dup pass: lane owns grid `lane` = 25 consecutive floats in the wave's
    // own LDS slice (stride 25 = 2-way bank aliasing, free). Wave reads only
    // its own writes -> compiler-managed lgkmcnt ordering, no barrier.
    ldup += grid_dups(wp + lane * 25);
}

__global__ __launch_bounds__(BLOCK, 1) void puzzle_main(
    const float* __restrict__ preds, const int* __restrict__ tgts,
    long long n_total,
    float* __restrict__ blk_sum, int* __restrict__ blk_dup,
    int* __restrict__ blk_oob)
{
    __shared__ float lds_p[WPB * TILE];     // 25600 B: one 6.4KB slice/wave
    __shared__ float s_sum[WPB];
    __shared__ int   s_dup[WPB];
    __shared__ int   s_oob[WPB];

    const int tid  = threadIdx.x;
    const int lane = tid & 63;
    const int wv   = tid >> 6;

    const long long total_tiles = n_total / TILE;
    const int total_waves = gridDim.x * WPB;
    const int gwave = blockIdx.x * WPB + wv;

    float* __restrict__ wp = &lds_p[wv * TILE];
    v4f* __restrict__ wp4 = reinterpret_cast<v4f*>(wp);

    float lsum = 0.0f;
    int   ldup = 0;
    float mn =  1e30f;
    float mx = -1e30f;

    // --- 2-stage software pipeline over this wave's ~5.33 tiles ---
    long long t0 = gwave;
    if (t0 < total_tiles) {
        TileRegs cur, nxt;
        load_tile(preds, tgts, t0, lane, cur);
        __builtin_amdgcn_sched_barrier(0);
        for (long long tn = t0 + total_waves; tn < total_tiles; tn += total_waves) {
            load_tile(preds, tgts, tn, lane, nxt);       // prefetch t+1
            __builtin_amdgcn_sched_barrier(0);           // pin: loads stay above
            compute_tile(cur, wp, wp4, lane, lsum, ldup, mn, mx);
            cur = nxt;                                   // register copy
        }
        compute_tile(cur, wp, wp4, lane, lsum, ldup, mn, mx);
    }

    // ragged tail (n % TILE != 0; n always a multiple of 25): direct global.
    const long long rem = n_total - total_tiles * TILE;
    if (rem > 0 && gwave == total_waves - 1) {
        const int ngrids = (int)(rem / 25);
        if (lane < ngrids) {
            const float* sp = preds + total_tiles * TILE + (long long)lane * 25;
            const int*   st = tgts  + total_tiles * TILE + (long long)lane * 25;
            float q[25];
            #pragma unroll
            for (int j = 0; j < 25; ++j) q[j] = sp[j];
            #pragma unroll
            for (int j = 0; j < 25; ++j) {
                lsum += fabsf(q[j] - (float)st[j]);
                mn = fminf(mn, q[j]);
                mx = fmaxf(mx, q[j]);
            }
            ldup += grid_dups(q);
        }
    }

    // wave reduction
    #pragma unroll
    for (int off = 32; off > 0; off >>= 1) {
        lsum += __shfl_down(lsum, off, 64);
        ldup += __shfl_down(ldup, off, 64);
        mn = fminf(mn, __shfl_down(mn, off, 64));
        mx = fmaxf(mx, __shfl_down(mx, off, 64));
    }
    if (lane == 0) {
        s_sum[wv] = lsum;
        s_dup[wv] = ldup;
        s_oob[wv] = (int)((mn < 0.5f) | (mx > 5.5f));
    }
    __syncthreads();
    if (tid == 0) {
        float bs = 0.0f; int bd = 0, bo = 0;
        #pragma unroll
        for (int w = 0; w < WPB; ++w) { bs += s_sum[w]; bd += s_dup[w]; bo |= s_oob[w]; }
        blk_sum[blockIdx.x] = bs;
        blk_dup[blockIdx.x] = bd;
        blk_oob[blockIdx.x] = bo;
    }
}

#define FBLOCK 256
#define FNWAVES (FBLOCK / 64)

__global__ __launch_bounds__(FBLOCK) void puzzle_final(
    const float* __restrict__ blk_sum, const int* __restrict__ blk_dup,
    const int* __restrict__ blk_oob, int nblocks,
    long long n_total, long long batch, float* __restrict__ out)
{
    __shared__ double s_sum[FNWAVES];
    __shared__ int    s_dup[FNWAVES];
    __shared__ int    s_oob[FNWAVES];

    double lsum = 0.0;
    int ldup = 0, loob = 0;
    for (int i = threadIdx.x; i < nblocks; i += FBLOCK) {
        lsum += (double)blk_sum[i];
        ldup += blk_dup[i];
        loob |= blk_oob[i];
    }
    #pragma unroll
    for (int off = 32; off > 0; off >>= 1) {
        lsum += __shfl_down(lsum, off, 64);
        ldup += __shfl_down(ldup, off, 64);
        loob |= __shfl_down(loob, off, 64);
    }
    const int wave = threadIdx.x >> 6;
    if ((threadIdx.x & 63) == 0) { s_sum[wave] = lsum; s_dup[wave] = ldup; s_oob[wave] = loob; }
    __syncthreads();
    if (threadIdx.x == 0) {
        double bs = 0.0; int bd = 0, bo = 0;
        #pragma unroll
        for (int w = 0; w < FNWAVES; ++w) { bs += s_sum[w]; bd += s_dup[w]; bo |= s_oob[w]; }
        const float loss1 = (float)(bs / (double)n_total);
        const float loss2 = (float)((double)bd * 0.1 / (double)batch);
        out[0] = loss1 + loss2 + (bo ? 1000.0f : 0.0f);
    }
}

extern "C" void kernel_launch(void* const* d_in, const int* in_sizes, int n_in,
                              void* d_out, int out_size, void* d_ws, size_t ws_size,
                              hipStream_t stream) {
    const float* preds = (const float*)d_in[0];
    const int*   tgts  = (const int*)d_in[1];
    float* out = (float*)d_out;

    const long long n = (long long)in_sizes[0];
    const long long batch = n / 25;

    // workspace layout: [float sums | int dups | int oobs], each NBLOCKS long
    float* blk_sum = (float*)d_ws;
    int*   blk_dup = (int*)(blk_sum + NBLOCKS);
    int*   blk_oob = (int*)(blk_dup + NBLOCKS);

    puzzle_main<<<NBLOCKS, BLOCK, 0, stream>>>(preds, tgts, n,
                                               blk_sum, blk_dup, blk_oob);
    puzzle_final<<<1, FBLOCK, 0, stream>>>(blk_sum, blk_dup, blk_oob,
                                           NBLOCKS, n, batch, out);
}